// Round 1
// baseline (3677.797 us; speedup 1.0000x reference)
//
#include <hip/hip_runtime.h>
#include <hip/hip_bf16.h>
#include <cstddef>

// Problem constants (LiteFlowNetCorr): B=8, C=128, H=128, W=224, R=4
#define BN 8
#define CCH 128
#define HH 128
#define WW 224
#define RR 4
#define ND 81           // (2R+1)^2 displacements
#define CH_IN 209       // C + 81

// ---------------------------------------------------------------------------
// Correlation: corr[b,d,y,x] = mean_c x1[b,c,y,x] * x2pad[b,c,y+dy,x+dx]
// Tile 16x16 pixels per block, loop channels, stage x2 24x24 halo tile in LDS.
// ---------------------------------------------------------------------------
__global__ __launch_bounds__(256) void corr_kernel(
    const float* __restrict__ x1, const float* __restrict__ x2,
    float* __restrict__ out) {
  __shared__ float s2[24 * 24];
  const int tx = threadIdx.x, ty = threadIdx.y;
  const int x0 = blockIdx.x * 16, y0 = blockIdx.y * 16, b = blockIdx.z;
  const int x = x0 + tx, y = y0 + ty;
  const int tid = ty * 16 + tx;

  float acc[ND];
#pragma unroll
  for (int i = 0; i < ND; ++i) acc[i] = 0.0f;

  for (int c = 0; c < CCH; ++c) {
    const float* p1 = x1 + ((size_t)(b * CCH + c)) * (HH * WW);
    const float* p2 = x2 + ((size_t)(b * CCH + c)) * (HH * WW);
    const float v1 = p1[y * WW + x];

    __syncthreads();  // protect previous iteration's s2 reads
    for (int i = tid; i < 24 * 24; i += 256) {
      const int r = i / 24, cc = i - r * 24;
      const int gy = y0 - RR + r, gx = x0 - RR + cc;
      s2[i] = (gy >= 0 && gy < HH && gx >= 0 && gx < WW) ? p2[gy * WW + gx]
                                                         : 0.0f;
    }
    __syncthreads();

#pragma unroll
    for (int dy = 0; dy < 9; ++dy) {
#pragma unroll
      for (int dx = 0; dx < 9; ++dx) {
        acc[dy * 9 + dx] += v1 * s2[(ty + dy) * 24 + (tx + dx)];
      }
    }
  }

  const float sc = 1.0f / 128.0f;
  for (int d = 0; d < ND; ++d) {
    out[(((size_t)b * ND + d) * HH + y) * WW + x] = acc[d] * sc;
  }
}

// ---------------------------------------------------------------------------
// Weight repack: OIHW (co, cin, 3, 3) -> (cin, co, 9) so the per-cin inner
// loop reads a contiguous block (scalar-load friendly, constant imm offsets).
// ---------------------------------------------------------------------------
__global__ void repack_w(const float* __restrict__ w, float* __restrict__ wt,
                         int COUT, int CIN) {
  const int idx = blockIdx.x * 256 + threadIdx.x;
  const int n = COUT * CIN * 9;
  if (idx >= n) return;
  const int co = idx / (CIN * 9);
  const int rem = idx - co * (CIN * 9);
  const int c = rem / 9;
  const int k = rem - c * 9;
  wt[(c * COUT + co) * 9 + k] = w[idx];
}

// ---------------------------------------------------------------------------
// Direct 3x3 SAME conv, thread-per-pixel, acc[COUT] in registers, input
// channel plane staged per-cin into an 18x18 LDS tile. Weights pre-repacked
// to (cin, co, 9): uniform addresses -> scalar loads feeding v_fma directly.
// Two input tensors support the implicit concat (in0 = x1, in1 = corr).
// ---------------------------------------------------------------------------
template <int CIN0, int CIN1, int COUT, bool LEAKY>
__global__ __launch_bounds__(256) void conv3x3_kernel(
    const float* __restrict__ in0, const float* __restrict__ in1,
    const float* __restrict__ wt, const float* __restrict__ bias,
    float* __restrict__ out) {
  constexpr int CIN = CIN0 + CIN1;
  __shared__ float tile[18 * 18];
  const int tx = threadIdx.x, ty = threadIdx.y;
  const int x0 = blockIdx.x * 16, y0 = blockIdx.y * 16, b = blockIdx.z;
  const int x = x0 + tx, y = y0 + ty;
  const int tid = ty * 16 + tx;

  float acc[COUT];
#pragma unroll
  for (int i = 0; i < COUT; ++i) acc[i] = bias[i];

  for (int c = 0; c < CIN; ++c) {
    const float* src;
    if constexpr (CIN1 > 0) {
      src = (c < CIN0)
                ? in0 + ((size_t)(b * CIN0 + c)) * (HH * WW)
                : in1 + ((size_t)(b * CIN1 + (c - CIN0))) * (HH * WW);
    } else {
      src = in0 + ((size_t)(b * CIN0 + c)) * (HH * WW);
    }

    __syncthreads();  // protect previous iteration's tile reads
    for (int i = tid; i < 18 * 18; i += 256) {
      const int r = i / 18, cc = i - r * 18;
      const int gy = y0 - 1 + r, gx = x0 - 1 + cc;
      tile[i] = (gy >= 0 && gy < HH && gx >= 0 && gx < WW) ? src[gy * WW + gx]
                                                           : 0.0f;
    }
    __syncthreads();

    float iv[9];
#pragma unroll
    for (int ky = 0; ky < 3; ++ky) {
#pragma unroll
      for (int kx = 0; kx < 3; ++kx) {
        iv[ky * 3 + kx] = tile[(ty + ky) * 18 + (tx + kx)];
      }
    }

    const float* wc = wt + (size_t)c * (COUT * 9);
#pragma unroll
    for (int co = 0; co < COUT; ++co) {
      float s = acc[co];
#pragma unroll
      for (int k = 0; k < 9; ++k) s += iv[k] * wc[co * 9 + k];
      acc[co] = s;
    }
  }

#pragma unroll
  for (int co = 0; co < COUT; ++co) {
    float v = acc[co];
    if (LEAKY) v = (v >= 0.0f) ? v : 0.1f * v;
    out[(((size_t)b * COUT + co) * HH + y) * WW + x] = v;
  }
}

// ---------------------------------------------------------------------------
// Launch
// ---------------------------------------------------------------------------
extern "C" void kernel_launch(void* const* d_in, const int* in_sizes, int n_in,
                              void* d_out, int out_size, void* d_ws,
                              size_t ws_size, hipStream_t stream) {
  const float* x1 = (const float*)d_in[0];
  const float* x2 = (const float*)d_in[1];
  const float* w1 = (const float*)d_in[2];
  const float* b1 = (const float*)d_in[3];
  const float* w2 = (const float*)d_in[4];
  const float* b2 = (const float*)d_in[5];
  const float* w3 = (const float*)d_in[6];
  const float* b3 = (const float*)d_in[7];
  const float* w4 = (const float*)d_in[8];
  const float* b4 = (const float*)d_in[9];
  float* out = (float*)d_out;

  // Workspace layout (bytes):
  //  [0, 74317824)            corr  (B*81*H*W f32)   -> later reused as h2
  //  [74317824, 133038080)    h1    (B*64*H*W f32)   -> later reused as h3
  //  [133038080, ...)         repacked weights (176256 floats = 705 KB)
  char* ws = (char*)d_ws;
  const size_t CORR_BYTES = (size_t)BN * ND * HH * WW * 4;       // 74,317,824
  const size_t H1_BYTES = (size_t)BN * 64 * HH * WW * 4;         // 58,720,256
  float* corr = (float*)ws;
  float* h1 = (float*)(ws + CORR_BYTES);
  float* h2 = (float*)ws;               // reuse corr space (corr dead)
  float* h3 = (float*)(ws + CORR_BYTES);// reuse h1 space   (h1 dead)
  float* wt1 = (float*)(ws + CORR_BYTES + H1_BYTES);
  float* wt2 = wt1 + 64 * CH_IN * 9;    // 120384
  float* wt3 = wt2 + 64 * 64 * 9;       // 36864
  float* wt4 = wt3 + 32 * 64 * 9;       // 18432

  // Repack weights (tiny kernels)
  {
    int n1 = 64 * CH_IN * 9;
    repack_w<<<(n1 + 255) / 256, 256, 0, stream>>>(w1, wt1, 64, CH_IN);
    int n2 = 64 * 64 * 9;
    repack_w<<<(n2 + 255) / 256, 256, 0, stream>>>(w2, wt2, 64, 64);
    int n3 = 32 * 64 * 9;
    repack_w<<<(n3 + 255) / 256, 256, 0, stream>>>(w3, wt3, 32, 64);
    int n4 = 2 * 32 * 9;
    repack_w<<<(n4 + 255) / 256, 256, 0, stream>>>(w4, wt4, 2, 32);
  }

  const dim3 grid(WW / 16, HH / 16, BN);  // 14 x 8 x 8
  const dim3 blk(16, 16);

  corr_kernel<<<grid, blk, 0, stream>>>(x1, x2, corr);

  conv3x3_kernel<128, 81, 64, true>
      <<<grid, blk, 0, stream>>>(x1, corr, wt1, b1, h1);
  conv3x3_kernel<64, 0, 64, true>
      <<<grid, blk, 0, stream>>>(h1, nullptr, wt2, b2, h2);
  conv3x3_kernel<64, 0, 32, true>
      <<<grid, blk, 0, stream>>>(h2, nullptr, wt3, b3, h3);
  conv3x3_kernel<32, 0, 2, false>
      <<<grid, blk, 0, stream>>>(h3, nullptr, wt4, b4, out);
}

// Round 2
// 2089.887 us; speedup vs baseline: 1.7598x; 1.7598x over previous
//
#include <hip/hip_runtime.h>
#include <hip/hip_bf16.h>
#include <cstddef>

// Problem constants (LiteFlowNetCorr): B=8, C=128, H=128, W=224, R=4
#define BN 8
#define CCH 128
#define HH 128
#define WW 224
#define RR 4
#define ND 81           // (2R+1)^2 displacements
#define CH_IN 209       // C + 81

// ---------------------------------------------------------------------------
// Correlation: corr[b,d,y,x] = mean_c x1[b,c,y,x] * x2pad[b,c,y+dy,x+dx]
// 16x16 pixel tile per block; x2 halo tile (24x24) in LDS per channel.
// launch_bounds(256,2): cap 256 VGPRs so acc[81] stays in registers.
// ---------------------------------------------------------------------------
__global__ __launch_bounds__(256, 2) void corr_kernel(
    const float* __restrict__ x1, const float* __restrict__ x2,
    float* __restrict__ out) {
  __shared__ float s2[24 * 24];
  const int tx = threadIdx.x, ty = threadIdx.y;
  const int x0 = blockIdx.x * 16, y0 = blockIdx.y * 16, b = blockIdx.z;
  const int x = x0 + tx, y = y0 + ty;
  const int tid = ty * 16 + tx;

  float acc[ND];
#pragma unroll
  for (int i = 0; i < ND; ++i) acc[i] = 0.0f;

  for (int c = 0; c < CCH; ++c) {
    const float* p1 = x1 + ((size_t)(b * CCH + c)) * (HH * WW);
    const float* p2 = x2 + ((size_t)(b * CCH + c)) * (HH * WW);
    const float v1 = p1[y * WW + x];

    __syncthreads();  // protect previous iteration's s2 reads
    for (int i = tid; i < 24 * 24; i += 256) {
      const int r = i / 24, cc = i - r * 24;
      const int gy = y0 - RR + r, gx = x0 - RR + cc;
      s2[i] = (gy >= 0 && gy < HH && gx >= 0 && gx < WW) ? p2[gy * WW + gx]
                                                         : 0.0f;
    }
    __syncthreads();

#pragma unroll
    for (int dy = 0; dy < 9; ++dy) {
#pragma unroll
      for (int dx = 0; dx < 9; ++dx) {
        acc[dy * 9 + dx] += v1 * s2[(ty + dy) * 24 + (tx + dx)];
      }
    }
  }

  const float sc = 1.0f / 128.0f;
#pragma unroll
  for (int d = 0; d < ND; ++d) {
    out[(((size_t)b * ND + d) * HH + y) * WW + x] = acc[d] * sc;
  }
}

// ---------------------------------------------------------------------------
// Weight repack: OIHW (co, cin, 3, 3) -> (cin, tap, co) so per-(cin,tap) the
// cout run is contiguous -> float4 broadcast reads from LDS.
// ---------------------------------------------------------------------------
__global__ void repack_w(const float* __restrict__ w, float* __restrict__ wt,
                         int COUT, int CIN) {
  const int idx = blockIdx.x * 256 + threadIdx.x;
  const int n = COUT * CIN * 9;
  if (idx >= n) return;
  const int co = idx / (CIN * 9);
  const int rem = idx - co * (CIN * 9);
  const int c = rem / 9;
  const int k = rem - c * 9;
  wt[(c * 9 + k) * COUT + co] = w[idx];
}

// ---------------------------------------------------------------------------
// Direct 3x3 SAME conv v2.
//  - 128 threads/block, tile 32 wide x 8 tall, 2 adjacent pixels per thread.
//  - acc[COUT][2] in registers (launch_bounds(128,2) -> 256 VGPR cap).
//  - 8-cin chunks: input halo tile (10x34) + weights ([cin][tap][co]) in LDS.
//  - Weight reads are block-uniform float4 -> LDS broadcast (conflict-free).
// ---------------------------------------------------------------------------
template <int CIN0, int CIN1, int COUT, bool LEAKY>
__global__ __launch_bounds__(128, 2) void conv3x3_v2(
    const float* __restrict__ in0, const float* __restrict__ in1,
    const float* __restrict__ wt, const float* __restrict__ bias,
    float* __restrict__ out) {
  constexpr int CIN = CIN0 + CIN1;
  constexpr int CHUNK = 8;
  constexpr int PLANE = 10 * 34;  // halo tile floats per cin

  __shared__ __align__(16) float sIn[CHUNK * PLANE];
  __shared__ __align__(16) float sW[CHUNK * 9 * COUT];

  const int tid = threadIdx.x;
  const int tx = tid & 15;        // 0..15 -> pixel pair column
  const int ty = tid >> 4;        // 0..7  -> row
  const int x0 = blockIdx.x * 32, y0 = blockIdx.y * 8, b = blockIdx.z;
  const int y = y0 + ty;
  const int xp = x0 + 2 * tx;     // first pixel x (even)

  float accA[COUT], accB[COUT];
#pragma unroll
  for (int co = 0; co < COUT; ++co) {
    accA[co] = bias[co];
    accB[co] = bias[co];
  }

  for (int cb = 0; cb < CIN; cb += CHUNK) {
    const int ccnt = (CIN - cb < CHUNK) ? (CIN - cb) : CHUNK;

    __syncthreads();  // protect previous chunk's LDS reads
    // --- stage input halo tiles (zero-padded) ---
    for (int i = tid; i < ccnt * PLANE; i += 128) {
      const int cs = i / PLANE;
      const int rem = i - cs * PLANE;
      const int r = rem / 34;
      const int col = rem - r * 34;
      const int gy = y0 - 1 + r, gx = x0 - 1 + col;
      const int g = cb + cs;
      const float* src;
      if constexpr (CIN1 > 0) {
        src = (g < CIN0) ? in0 + ((size_t)(b * CIN0 + g)) * (HH * WW)
                         : in1 + ((size_t)(b * CIN1 + (g - CIN0))) * (HH * WW);
      } else {
        src = in0 + ((size_t)(b * CIN0 + g)) * (HH * WW);
      }
      sIn[i] = (gy >= 0 && gy < HH && gx >= 0 && gx < WW) ? src[gy * WW + gx]
                                                          : 0.0f;
    }
    // --- stage weights (contiguous copy thanks to [cin][tap][co] layout) ---
    for (int i = tid; i < ccnt * 9 * COUT; i += 128) {
      sW[i] = wt[(size_t)cb * 9 * COUT + i];
    }
    __syncthreads();

    for (int cs = 0; cs < ccnt; ++cs) {
      // load 3x4 input window for the pixel pair
      float iv[3][4];
#pragma unroll
      for (int r = 0; r < 3; ++r) {
        const float2 p =
            *(const float2*)&sIn[(cs * 10 + ty + r) * 34 + 2 * tx];
        const float2 q =
            *(const float2*)&sIn[(cs * 10 + ty + r) * 34 + 2 * tx + 2];
        iv[r][0] = p.x; iv[r][1] = p.y; iv[r][2] = q.x; iv[r][3] = q.y;
      }

#pragma unroll
      for (int ky = 0; ky < 3; ++ky) {
#pragma unroll
        for (int kx = 0; kx < 3; ++kx) {
          const int k = ky * 3 + kx;
          const float v0 = iv[ky][kx];
          const float v1 = iv[ky][kx + 1];
          if constexpr (COUT % 4 == 0) {
#pragma unroll
            for (int c4 = 0; c4 < COUT / 4; ++c4) {
              const float4 w = *(const float4*)&sW[(cs * 9 + k) * COUT + c4 * 4];
              accA[c4 * 4 + 0] += w.x * v0; accB[c4 * 4 + 0] += w.x * v1;
              accA[c4 * 4 + 1] += w.y * v0; accB[c4 * 4 + 1] += w.y * v1;
              accA[c4 * 4 + 2] += w.z * v0; accB[c4 * 4 + 2] += w.z * v1;
              accA[c4 * 4 + 3] += w.w * v0; accB[c4 * 4 + 3] += w.w * v1;
            }
          } else {
#pragma unroll
            for (int co = 0; co < COUT; ++co) {
              const float w = sW[(cs * 9 + k) * COUT + co];
              accA[co] += w * v0;
              accB[co] += w * v1;
            }
          }
        }
      }
    }
  }

#pragma unroll
  for (int co = 0; co < COUT; ++co) {
    float2 v = make_float2(accA[co], accB[co]);
    if (LEAKY) {
      v.x = (v.x >= 0.0f) ? v.x : 0.1f * v.x;
      v.y = (v.y >= 0.0f) ? v.y : 0.1f * v.y;
    }
    *(float2*)&out[(((size_t)b * COUT + co) * HH + y) * WW + xp] = v;
  }
}

// ---------------------------------------------------------------------------
// Launch
// ---------------------------------------------------------------------------
extern "C" void kernel_launch(void* const* d_in, const int* in_sizes, int n_in,
                              void* d_out, int out_size, void* d_ws,
                              size_t ws_size, hipStream_t stream) {
  const float* x1 = (const float*)d_in[0];
  const float* x2 = (const float*)d_in[1];
  const float* w1 = (const float*)d_in[2];
  const float* b1 = (const float*)d_in[3];
  const float* w2 = (const float*)d_in[4];
  const float* b2 = (const float*)d_in[5];
  const float* w3 = (const float*)d_in[6];
  const float* b3 = (const float*)d_in[7];
  const float* w4 = (const float*)d_in[8];
  const float* b4 = (const float*)d_in[9];
  float* out = (float*)d_out;

  // Workspace layout (bytes):
  //  [0, 74317824)            corr  (B*81*H*W f32)   -> later reused as h2
  //  [74317824, 133038080)    h1    (B*64*H*W f32)   -> later reused as h3
  //  [133038080, ...)         repacked weights (176256 floats = 705 KB)
  char* ws = (char*)d_ws;
  const size_t CORR_BYTES = (size_t)BN * ND * HH * WW * 4;        // 74,317,824
  const size_t H1_BYTES = (size_t)BN * 64 * HH * WW * 4;          // 58,720,256
  float* corr = (float*)ws;
  float* h1 = (float*)(ws + CORR_BYTES);
  float* h2 = (float*)ws;                // reuse corr space (corr dead)
  float* h3 = (float*)(ws + CORR_BYTES); // reuse h1 space   (h1 dead)
  float* wt1 = (float*)(ws + CORR_BYTES + H1_BYTES);
  float* wt2 = wt1 + 64 * CH_IN * 9;     // 120384 floats
  float* wt3 = wt2 + 64 * 64 * 9;        // 36864
  float* wt4 = wt3 + 32 * 64 * 9;        // 18432

  {
    int n1 = 64 * CH_IN * 9;
    repack_w<<<(n1 + 255) / 256, 256, 0, stream>>>(w1, wt1, 64, CH_IN);
    int n2 = 64 * 64 * 9;
    repack_w<<<(n2 + 255) / 256, 256, 0, stream>>>(w2, wt2, 64, 64);
    int n3 = 32 * 64 * 9;
    repack_w<<<(n3 + 255) / 256, 256, 0, stream>>>(w3, wt3, 32, 64);
    int n4 = 2 * 32 * 9;
    repack_w<<<(n4 + 255) / 256, 256, 0, stream>>>(w4, wt4, 2, 32);
  }

  const dim3 cgrid(WW / 16, HH / 16, BN);  // 14 x 8 x 8
  const dim3 cblk(16, 16);
  corr_kernel<<<cgrid, cblk, 0, stream>>>(x1, x2, corr);

  const dim3 grid(WW / 32, HH / 8, BN);    // 7 x 16 x 8 = 896 blocks
  const dim3 blk(128);

  conv3x3_v2<128, 81, 64, true><<<grid, blk, 0, stream>>>(x1, corr, wt1, b1, h1);
  conv3x3_v2<64, 0, 64, true><<<grid, blk, 0, stream>>>(h1, nullptr, wt2, b2, h2);
  conv3x3_v2<64, 0, 32, true><<<grid, blk, 0, stream>>>(h2, nullptr, wt3, b3, h3);
  conv3x3_v2<32, 0, 2, false><<<grid, blk, 0, stream>>>(h3, nullptr, wt4, b4, out);
}

// Round 3
// 1168.595 us; speedup vs baseline: 3.1472x; 1.7884x over previous
//
#include <hip/hip_runtime.h>
#include <hip/hip_bf16.h>
#include <cstddef>

// Problem constants (LiteFlowNetCorr): B=8, C=128, H=128, W=224, R=4
#define BN 8
#define CCH 128
#define HH 128
#define WW 224
#define ND 81            // (2R+1)^2 displacements
#define CINP1 224        // conv1 K padded: 128 (x1) + 81 (corr) + 15 zeros

typedef __attribute__((ext_vector_type(8))) short short8_t;   // 8 bf16
typedef __attribute__((ext_vector_type(4))) float float4_t;   // MFMA acc

static __device__ __forceinline__ unsigned short f2bf(float f) {
  __hip_bfloat16 h = __float2bfloat16(f);
  return *(unsigned short*)&h;
}
static __device__ __forceinline__ float bf2f(short s) {
  unsigned u = ((unsigned)(unsigned short)s) << 16;
  return __uint_as_float(u);
}

// ---------------------------------------------------------------------------
// convert_x1: x1 fp32 NCHW -> A0 bf16 NHWC (channels 0..127), zero-fill the
// pad chunks so channels 209..223 are 0 (corr later fills 128..208).
// A0 record = 224 ch * 2B = 448 B = 28 uint4 chunks per pixel.
// ---------------------------------------------------------------------------
__global__ __launch_bounds__(256) void convert_x1(
    const float* __restrict__ x1, uint4* __restrict__ a0q) {
  const int g = blockIdx.x * 256 + threadIdx.x;  // pixel id 0..229375
  const int hw = HH * WW;
  const int b = g / hw, px = g - b * hw;
  const float* src = x1 + (size_t)b * CCH * hw + px;

  uint4 zero; zero.x = zero.y = zero.z = zero.w = 0u;
#pragma unroll
  for (int cq = 0; cq < 16; ++cq) {  // 16 chunks = 128 channels
    unsigned r[4];
#pragma unroll
    for (int j = 0; j < 4; ++j) {
      const int c = cq * 8 + j * 2;
      const float f0 = src[(size_t)(c + 0) * hw];
      const float f1 = src[(size_t)(c + 1) * hw];
      r[j] = (unsigned)f2bf(f0) | ((unsigned)f2bf(f1) << 16);
    }
    uint4 u; u.x = r[0]; u.y = r[1]; u.z = r[2]; u.w = r[3];
    a0q[(size_t)g * 28 + cq] = u;
  }
  a0q[(size_t)g * 28 + 26] = zero;  // ch 208..215 (corr overwrites ch208)
  a0q[(size_t)g * 28 + 27] = zero;  // ch 216..223
}

// ---------------------------------------------------------------------------
// corr_v2: fp32 NCHW inputs, bf16 NHWC output into A0 channels 128..208.
// Tile 32x32 px, 256 thr (tx 0..7 -> 4 px each, ty 0..31). x2 halo 40x40 in
// LDS per channel. d split into 3 chunks of 27 (3 dy rows each): acc[27][4].
// Window reads are aligned ds_read_b128 (f[16] covers all dx for 4 px).
// ---------------------------------------------------------------------------
__global__ __launch_bounds__(256, 2) void corr_v2(
    const float* __restrict__ x1, const float* __restrict__ x2,
    __hip_bfloat16* __restrict__ a0) {
  __shared__ float s2[40 * 40];
  const int tid = threadIdx.x;
  const int tx = tid & 7, ty = tid >> 3;
  const int x0 = blockIdx.x * 32, y0 = blockIdx.y * 32, b = blockIdx.z;
  const int y = y0 + ty, xbase = x0 + 4 * tx;
  const int hw = HH * WW;
  const float sc = 1.0f / 128.0f;

  for (int dc = 0; dc < 3; ++dc) {
    float acc[27][4];
#pragma unroll
    for (int i = 0; i < 27; ++i)
#pragma unroll
      for (int p = 0; p < 4; ++p) acc[i][p] = 0.0f;

    for (int c = 0; c < CCH; ++c) {
      const float* p1 = x1 + (size_t)(b * CCH + c) * hw;
      const float* p2 = x2 + (size_t)(b * CCH + c) * hw;

      __syncthreads();
      for (int s = tid; s < 400; s += 256) {  // 40 rows x 10 float4 cols
        const int r = s / 10, c4 = s - r * 10;
        const int gy = y0 - 4 + r;
        const int gx = x0 - 4 + c4 * 4;
        float4 v;
        if (gy >= 0 && gy < HH && gx >= 0 && gx + 3 < WW) {
          v = *(const float4*)&p2[gy * WW + gx];
        } else {
          v.x = (gy >= 0 && gy < HH && gx + 0 >= 0 && gx + 0 < WW) ? p2[gy * WW + gx + 0] : 0.0f;
          v.y = (gy >= 0 && gy < HH && gx + 1 >= 0 && gx + 1 < WW) ? p2[gy * WW + gx + 1] : 0.0f;
          v.z = (gy >= 0 && gy < HH && gx + 2 >= 0 && gx + 2 < WW) ? p2[gy * WW + gx + 2] : 0.0f;
          v.w = (gy >= 0 && gy < HH && gx + 3 >= 0 && gx + 3 < WW) ? p2[gy * WW + gx + 3] : 0.0f;
        }
        *(float4*)&s2[r * 40 + c4 * 4] = v;
      }
      __syncthreads();

      const float4 v1 = *(const float4*)&p1[y * WW + xbase];
      const float v1a[4] = {v1.x, v1.y, v1.z, v1.w};

#pragma unroll
      for (int dyi = 0; dyi < 3; ++dyi) {
        const int row = ty + dc * 3 + dyi;  // = ty + (dy+4)
        float f[16];
        const float4 f0 = *(const float4*)&s2[row * 40 + 4 * tx + 0];
        const float4 f1 = *(const float4*)&s2[row * 40 + 4 * tx + 4];
        const float4 f2 = *(const float4*)&s2[row * 40 + 4 * tx + 8];
        const float4 f3 = *(const float4*)&s2[row * 40 + 4 * tx + 12];
        f[0]=f0.x; f[1]=f0.y; f[2]=f0.z; f[3]=f0.w;
        f[4]=f1.x; f[5]=f1.y; f[6]=f1.z; f[7]=f1.w;
        f[8]=f2.x; f[9]=f2.y; f[10]=f2.z; f[11]=f2.w;
        f[12]=f3.x; f[13]=f3.y; f[14]=f3.z; f[15]=f3.w;
#pragma unroll
        for (int dx = 0; dx < 9; ++dx)
#pragma unroll
          for (int p = 0; p < 4; ++p)
            acc[dyi * 9 + dx][p] += v1a[p] * f[p + dx];
      }
    }

    // epilogue: 27 channels for 4 pixels -> bf16 scatter into A0
#pragma unroll
    for (int p = 0; p < 4; ++p) {
      const size_t gp = ((size_t)(b * HH + y) * WW + xbase + p);
      __hip_bfloat16* dst = a0 + gp * CINP1 + 128 + dc * 27;
#pragma unroll
      for (int d = 0; d < 27; ++d) {
        dst[d] = __float2bfloat16(acc[d][p] * sc);
      }
    }
  }
}

// ---------------------------------------------------------------------------
// Weight repack: OIHW fp32 -> bf16 [tap][cout][cin_pad] (zero-pad cin tail).
// ---------------------------------------------------------------------------
__global__ void repack_w_bf16(const float* __restrict__ w,
                              __hip_bfloat16* __restrict__ wt,
                              int COUT, int CIN, int CINPAD) {
  const int idx = blockIdx.x * 256 + threadIdx.x;
  const int n = 9 * COUT * CINPAD;
  if (idx >= n) return;
  const int t = idx / (COUT * CINPAD);
  const int rem = idx - t * (COUT * CINPAD);
  const int co = rem / CINPAD;
  const int ci = rem - co * CINPAD;
  const float v = (ci < CIN) ? w[(size_t)(co * CIN + ci) * 9 + t] : 0.0f;
  wt[idx] = __float2bfloat16(v);
}

// ---------------------------------------------------------------------------
// conv_mfma: implicit-GEMM 3x3 SAME conv, bf16 NHWC in -> bf16 NHWC out.
// Block: 256 thr = 4 waves; out tile 16x16 px; wave w owns y-rows 4w..4w+3.
// K loop: cin blocks of 32; per cb stage A halo (18x18 px, 32ch) and W chunk
// ([9][COUT][32]) in LDS as SoA 16B chunks (2-way max bank aliasing).
// MFMA 16x16x32 bf16: A[m=px_x][k=cin], B[k][n=cout].
// ---------------------------------------------------------------------------
template <int CINPAD, int COUT, bool LEAKY>
__global__ __launch_bounds__(256, 2) void conv_mfma(
    const uint4* __restrict__ inq,          // bf16 NHWC, CINPAD ch/px
    const __hip_bfloat16* __restrict__ wt,  // [9][COUT][CINPAD]
    const float* __restrict__ bias,
    __hip_bfloat16* __restrict__ out) {     // bf16 NHWC, COUT ch/px
  constexpr int NT = COUT / 16;
  constexpr int NCB = CINPAD / 32;
  constexpr int QSTRIDE_A = 324;          // 18*18 px slots per q-plane
  __shared__ uint4 sA[4 * QSTRIDE_A];     // [q][p]
  __shared__ uint4 sW[4 * 9 * COUT];      // [q][t][co]

  const int tid = threadIdx.x;
  const int lane = tid & 63, w = tid >> 6;
  const int m = lane & 15, q = lane >> 4;
  const int x0 = blockIdx.x * 16, y0 = blockIdx.y * 16, b = blockIdx.z;
  const uint4* wq = (const uint4*)wt;

  float4_t acc[4][NT];
#pragma unroll
  for (int my = 0; my < 4; ++my)
#pragma unroll
    for (int nt = 0; nt < NT; ++nt) acc[my][nt] = (float4_t)0.0f;

  for (int cb = 0; cb < NCB; ++cb) {
    __syncthreads();
    // --- stage A halo tile: 18x18 px, chunks cb*4 .. cb*4+3 ---
    for (int s = tid; s < 324; s += 256) {
      const int pr = s / 18, pc = s - pr * 18;
      const int gy = y0 - 1 + pr, gx = x0 - 1 + pc;
      uint4 c0, c1, c2, c3;
      if (gy >= 0 && gy < HH && gx >= 0 && gx < WW) {
        const size_t base =
            ((size_t)(b * HH + gy) * WW + gx) * (CINPAD / 8) + cb * 4;
        c0 = inq[base + 0]; c1 = inq[base + 1];
        c2 = inq[base + 2]; c3 = inq[base + 3];
      } else {
        c0.x=c0.y=c0.z=c0.w=0u; c1=c0; c2=c0; c3=c0;
      }
      sA[0 * QSTRIDE_A + s] = c0;
      sA[1 * QSTRIDE_A + s] = c1;
      sA[2 * QSTRIDE_A + s] = c2;
      sA[3 * QSTRIDE_A + s] = c3;
    }
    // --- stage W chunk: [9][COUT][32ch] ---
    for (int s = tid; s < 9 * COUT; s += 256) {
      const int t = s / COUT, co = s - t * COUT;
      const size_t base = ((size_t)(t * COUT + co) * CINPAD + cb * 32) / 8;
      const uint4 c0 = wq[base + 0], c1 = wq[base + 1];
      const uint4 c2 = wq[base + 2], c3 = wq[base + 3];
      sW[(0 * 9 + t) * COUT + co] = c0;
      sW[(1 * 9 + t) * COUT + co] = c1;
      sW[(2 * 9 + t) * COUT + co] = c2;
      sW[(3 * 9 + t) * COUT + co] = c3;
    }
    __syncthreads();

#pragma unroll
    for (int t = 0; t < 9; ++t) {
      const int dy = t / 3 - 1, dx = t % 3 - 1;
      short8_t bf[NT];
#pragma unroll
      for (int nt = 0; nt < NT; ++nt) {
        bf[nt] = *(const short8_t*)&sW[(q * 9 + t) * COUT + nt * 16 + m];
      }
#pragma unroll
      for (int my = 0; my < 4; ++my) {
        const int row = 4 * w + my + dy + 1;
        const int col = m + dx + 1;
        const short8_t af =
            *(const short8_t*)&sA[q * QSTRIDE_A + row * 18 + col];
#pragma unroll
        for (int nt = 0; nt < NT; ++nt) {
          acc[my][nt] = __builtin_amdgcn_mfma_f32_16x16x32_bf16(
              af, bf[nt], acc[my][nt], 0, 0, 0);
        }
      }
    }
  }

  // --- epilogue: bias + leaky + bf16 NHWC store ---
  // C/D layout: col(n)=lane&15, row(m)=(lane>>4)*4+r
#pragma unroll
  for (int my = 0; my < 4; ++my) {
    const int y = y0 + 4 * w + my;
#pragma unroll
    for (int nt = 0; nt < NT; ++nt) {
      const int co = nt * 16 + m;
      const float bv = bias[co];
#pragma unroll
      for (int r = 0; r < 4; ++r) {
        const int x = x0 + q * 4 + r;
        float v = acc[my][nt][r] + bv;
        if (LEAKY) v = (v >= 0.0f) ? v : 0.1f * v;
        out[((size_t)(b * HH + y) * WW + x) * COUT + co] = __float2bfloat16(v);
      }
    }
  }
}

// ---------------------------------------------------------------------------
// conv4: 32 -> 2, direct, bf16 NHWC in -> fp32 NCHW out (final flow).
// ---------------------------------------------------------------------------
__global__ __launch_bounds__(256, 2) void conv4_kernel(
    const uint4* __restrict__ inq,          // h3, 32ch/px = 4 uint4
    const __hip_bfloat16* __restrict__ wt,  // [9][2][32]
    const float* __restrict__ bias,
    float* __restrict__ out) {
  __shared__ uint4 sA[4 * 324];
  __shared__ uint4 sW[9 * 2 * 4];  // [t][co][q]
  const int tid = threadIdx.x;
  const int tx = tid & 15, ty = tid >> 4;
  const int x0 = blockIdx.x * 16, y0 = blockIdx.y * 16, b = blockIdx.z;

  for (int s = tid; s < 324; s += 256) {
    const int pr = s / 18, pc = s - pr * 18;
    const int gy = y0 - 1 + pr, gx = x0 - 1 + pc;
    uint4 c0, c1, c2, c3;
    if (gy >= 0 && gy < HH && gx >= 0 && gx < WW) {
      const size_t base = ((size_t)(b * HH + gy) * WW + gx) * 4;
      c0 = inq[base + 0]; c1 = inq[base + 1];
      c2 = inq[base + 2]; c3 = inq[base + 3];
    } else {
      c0.x=c0.y=c0.z=c0.w=0u; c1=c0; c2=c0; c3=c0;
    }
    sA[0 * 324 + s] = c0; sA[1 * 324 + s] = c1;
    sA[2 * 324 + s] = c2; sA[3 * 324 + s] = c3;
  }
  if (tid < 72) sW[tid] = ((const uint4*)wt)[tid];
  __syncthreads();

  float acc0 = bias[0], acc1 = bias[1];
#pragma unroll
  for (int t = 0; t < 9; ++t) {
    const int dy = t / 3 - 1, dx = t % 3 - 1;
    const int row = ty + dy + 1, col = tx + dx + 1;
#pragma unroll
    for (int qi = 0; qi < 4; ++qi) {
      const short8_t a = *(const short8_t*)&sA[qi * 324 + row * 18 + col];
      const short8_t w0 = *(const short8_t*)&sW[(t * 2 + 0) * 4 + qi];
      const short8_t w1 = *(const short8_t*)&sW[(t * 2 + 1) * 4 + qi];
#pragma unroll
      for (int j = 0; j < 8; ++j) {
        const float av = bf2f(a[j]);
        acc0 += av * bf2f(w0[j]);
        acc1 += av * bf2f(w1[j]);
      }
    }
  }
  const int y = y0 + ty, x = x0 + tx;
  out[((size_t)(b * 2 + 0) * HH + y) * WW + x] = acc0;
  out[((size_t)(b * 2 + 1) * HH + y) * WW + x] = acc1;
}

// ---------------------------------------------------------------------------
// Launch
// ---------------------------------------------------------------------------
extern "C" void kernel_launch(void* const* d_in, const int* in_sizes, int n_in,
                              void* d_out, int out_size, void* d_ws,
                              size_t ws_size, hipStream_t stream) {
  const float* x1 = (const float*)d_in[0];
  const float* x2 = (const float*)d_in[1];
  const float* w1 = (const float*)d_in[2];
  const float* b1 = (const float*)d_in[3];
  const float* w2 = (const float*)d_in[4];
  const float* b2 = (const float*)d_in[5];
  const float* w3 = (const float*)d_in[6];
  const float* b3 = (const float*)d_in[7];
  const float* w4 = (const float*)d_in[8];
  const float* b4 = (const float*)d_in[9];
  float* out = (float*)d_out;

  // Workspace (bytes):
  //  A0  [0, 102760448)              bf16 NHWC 224ch concat (x1+corr+pad)
  //  h1  [102760448, 132120576)      bf16 NHWC 64ch
  //  wt1 [132120576, +258048)        bf16 [9][64][224]
  //  wt2 ... [9][64][64], wt3 [9][32][64], wt4 [9][2][32]
  //  h2 reuses A0[0, 29360128)  (A0 dead after conv1)
  //  h3 reuses A0[29360128, 44040192)
  char* ws = (char*)d_ws;
  __hip_bfloat16* A0 = (__hip_bfloat16*)ws;
  const size_t A0_BYTES = (size_t)BN * HH * WW * CINP1 * 2;  // 102,760,448
  __hip_bfloat16* h1 = (__hip_bfloat16*)(ws + A0_BYTES);
  const size_t H1_BYTES = (size_t)BN * HH * WW * 64 * 2;     // 29,360,128
  __hip_bfloat16* wt1 = (__hip_bfloat16*)(ws + A0_BYTES + H1_BYTES);
  __hip_bfloat16* wt2 = wt1 + 9 * 64 * CINP1;
  __hip_bfloat16* wt3 = wt2 + 9 * 64 * 64;
  __hip_bfloat16* wt4 = wt3 + 9 * 32 * 64;
  __hip_bfloat16* h2 = (__hip_bfloat16*)ws;
  __hip_bfloat16* h3 = (__hip_bfloat16*)(ws + H1_BYTES);

  // weight repacks (tiny)
  {
    int n1 = 9 * 64 * CINP1;
    repack_w_bf16<<<(n1 + 255) / 256, 256, 0, stream>>>(w1, wt1, 64, 209, CINP1);
    int n2 = 9 * 64 * 64;
    repack_w_bf16<<<(n2 + 255) / 256, 256, 0, stream>>>(w2, wt2, 64, 64, 64);
    int n3 = 9 * 32 * 64;
    repack_w_bf16<<<(n3 + 255) / 256, 256, 0, stream>>>(w3, wt3, 32, 64, 64);
    int n4 = 9 * 2 * 32;
    repack_w_bf16<<<(n4 + 255) / 256, 256, 0, stream>>>(w4, wt4, 2, 32, 32);
  }

  // x1 -> A0 (bf16 NHWC) + zero pad channels
  convert_x1<<<BN * HH * WW / 256, 256, 0, stream>>>(x1, (uint4*)A0);

  // correlation -> A0 channels 128..208
  corr_v2<<<dim3(WW / 32, HH / 32, BN), dim3(256), 0, stream>>>(x1, x2, A0);

  const dim3 grid(WW / 16, HH / 16, BN);  // 14 x 8 x 8 = 896 blocks
  conv_mfma<CINP1, 64, true>
      <<<grid, 256, 0, stream>>>((const uint4*)A0, wt1, b1, h1);
  conv_mfma<64, 64, true>
      <<<grid, 256, 0, stream>>>((const uint4*)h1, wt2, b2, h2);
  conv_mfma<64, 32, true>
      <<<grid, 256, 0, stream>>>((const uint4*)h2, wt3, b3, h3);
  conv4_kernel<<<grid, 256, 0, stream>>>((const uint4*)h3, wt4, b4, out);
}

// Round 4
// 723.109 us; speedup vs baseline: 5.0861x; 1.6161x over previous
//
#include <hip/hip_runtime.h>
#include <hip/hip_bf16.h>
#include <cstddef>

// Problem constants (LiteFlowNetCorr): B=8, C=128, H=128, W=224, R=4
#define BN 8
#define CCH 128
#define HH 128
#define WW 224
#define ND 81            // (2R+1)^2 displacements
#define CINP1 224        // conv1 K padded: 128 (x1) + 81 (corr) + 15 zeros

typedef __attribute__((ext_vector_type(8))) short short8_t;   // 8 bf16
typedef __attribute__((ext_vector_type(4))) float float4_t;   // MFMA acc

static __device__ __forceinline__ unsigned short f2bf(float f) {
  __hip_bfloat16 h = __float2bfloat16(f);
  return *(unsigned short*)&h;
}
static __device__ __forceinline__ float bf2f(short s) {
  unsigned u = ((unsigned)(unsigned short)s) << 16;
  return __uint_as_float(u);
}

// ---------------------------------------------------------------------------
// convert_x1: x1 fp32 NCHW -> A0 bf16 NHWC (channels 0..127), zero-fill the
// pad chunks so channels 209..223 are 0 (corr later fills 128..208).
// A0 record = 224 ch * 2B = 448 B = 28 uint4 chunks per pixel.
// ---------------------------------------------------------------------------
__global__ __launch_bounds__(256) void convert_x1(
    const float* __restrict__ x1, uint4* __restrict__ a0q) {
  const int g = blockIdx.x * 256 + threadIdx.x;  // pixel id 0..229375
  const int hw = HH * WW;
  const int b = g / hw, px = g - b * hw;
  const float* src = x1 + (size_t)b * CCH * hw + px;

  uint4 zero; zero.x = zero.y = zero.z = zero.w = 0u;
#pragma unroll
  for (int cq = 0; cq < 16; ++cq) {  // 16 chunks = 128 channels
    unsigned r[4];
#pragma unroll
    for (int j = 0; j < 4; ++j) {
      const int c = cq * 8 + j * 2;
      const float f0 = src[(size_t)(c + 0) * hw];
      const float f1 = src[(size_t)(c + 1) * hw];
      r[j] = (unsigned)f2bf(f0) | ((unsigned)f2bf(f1) << 16);
    }
    uint4 u; u.x = r[0]; u.y = r[1]; u.z = r[2]; u.w = r[3];
    a0q[(size_t)g * 28 + cq] = u;
  }
  a0q[(size_t)g * 28 + 26] = zero;  // ch 208..215 (corr overwrites ch208)
  a0q[(size_t)g * 28 + 27] = zero;  // ch 216..223
}

// ---------------------------------------------------------------------------
// corr_v3: single pass over channels, all 81 displacements at once.
//  - Block: 192 threads = 3 waves. Pixel tile 16x16; every wave covers all
//    256 px (4 px/thread: lane -> tx=lane&3 (x=4*tx..), ty=lane>>2).
//  - Displacements split by dy across waves: wave w handles dy rows
//    3w..3w+2 -> 27 d, acc[27][4] = 108 VGPRs (no spill, no re-pass).
//  - x2 halo 24x24 fp32 staged per 4-channel group (9.2 KB LDS).
//  - Window read: 3 aligned ds_read_b128 per (c,row) -> f[12] covers
//    9 dx for 4 px -> 36 FMA per 3 LDS ops (VALU-bound 2:1).
//  - Output: bf16 scatter into A0 channels 128..208 (NHWC concat).
// ---------------------------------------------------------------------------
#define CPC 4  // channels staged per barrier
__global__ __launch_bounds__(192, 2) void corr_v3(
    const float* __restrict__ x1, const float* __restrict__ x2,
    __hip_bfloat16* __restrict__ a0) {
  __shared__ float s2[CPC][24 * 24];
  const int tid = threadIdx.x;
  const int lane = tid & 63, w = tid >> 6;       // 3 waves
  const int tx = lane & 3, ty = lane >> 2;
  const int x0 = blockIdx.x * 16, y0 = blockIdx.y * 16, b = blockIdx.z;
  const int y = y0 + ty;
  const int xb = x0 + 4 * tx;
  const int hw = HH * WW;

  float acc[27][4];
#pragma unroll
  for (int i = 0; i < 27; ++i)
#pragma unroll
    for (int p = 0; p < 4; ++p) acc[i][p] = 0.0f;

  for (int cb = 0; cb < CCH; cb += CPC) {
    __syncthreads();  // protect previous group's s2 reads
    // stage CPC channel halos: 24 rows x 6 float4 per channel = 144 f4/ch
    for (int s = tid; s < CPC * 144; s += 192) {
      const int cs = s / 144, r4 = s - cs * 144;
      const int r = r4 / 6, c4 = r4 - r * 6;
      const int gy = y0 - 4 + r, gx = x0 - 4 + c4 * 4;
      const float* p2 = x2 + (size_t)(b * CCH + cb + cs) * hw;
      float4 v;
      if (gy >= 0 && gy < HH && gx >= 0 && gx + 3 < WW) {
        v = *(const float4*)&p2[gy * WW + gx];
      } else {
        v.x = (gy >= 0 && gy < HH && gx + 0 >= 0 && gx + 0 < WW) ? p2[gy * WW + gx + 0] : 0.0f;
        v.y = (gy >= 0 && gy < HH && gx + 1 >= 0 && gx + 1 < WW) ? p2[gy * WW + gx + 1] : 0.0f;
        v.z = (gy >= 0 && gy < HH && gx + 2 >= 0 && gx + 2 < WW) ? p2[gy * WW + gx + 2] : 0.0f;
        v.w = (gy >= 0 && gy < HH && gx + 3 >= 0 && gx + 3 < WW) ? p2[gy * WW + gx + 3] : 0.0f;
      }
      *(float4*)&s2[cs][r * 24 + c4 * 4] = v;
    }
    __syncthreads();

#pragma unroll
    for (int cs = 0; cs < CPC; ++cs) {
      const float* p1 = x1 + (size_t)(b * CCH + cb + cs) * hw;
      const float4 v1 = *(const float4*)&p1[y * WW + xb];
      const float v1a[4] = {v1.x, v1.y, v1.z, v1.w};

#pragma unroll
      for (int r = 0; r < 3; ++r) {
        const int row = ty + 3 * w + r;  // = ty + dy, dy = 3w + r
        float f[12];
        const float4 f0 = *(const float4*)&s2[cs][row * 24 + 4 * tx + 0];
        const float4 f1 = *(const float4*)&s2[cs][row * 24 + 4 * tx + 4];
        const float4 f2 = *(const float4*)&s2[cs][row * 24 + 4 * tx + 8];
        f[0]=f0.x; f[1]=f0.y; f[2]=f0.z; f[3]=f0.w;
        f[4]=f1.x; f[5]=f1.y; f[6]=f1.z; f[7]=f1.w;
        f[8]=f2.x; f[9]=f2.y; f[10]=f2.z; f[11]=f2.w;
#pragma unroll
        for (int dx = 0; dx < 9; ++dx)
#pragma unroll
          for (int p = 0; p < 4; ++p)
            acc[r * 9 + dx][p] += v1a[p] * f[p + dx];
      }
    }
  }

  // epilogue: wave w owns global d = 27w + (r*9+dx); bf16 scatter into A0
  const float sc = 1.0f / 128.0f;
#pragma unroll
  for (int p = 0; p < 4; ++p) {
    const size_t gp = ((size_t)(b * HH + y) * WW + xb + p);
    __hip_bfloat16* dst = a0 + gp * CINP1 + 128 + 27 * w;
#pragma unroll
    for (int d = 0; d < 27; ++d) {
      dst[d] = __float2bfloat16(acc[d][p] * sc);
    }
  }
}

// ---------------------------------------------------------------------------
// Weight repack: OIHW fp32 -> bf16 [tap][cout][cin_pad] (zero-pad cin tail).
// ---------------------------------------------------------------------------
__global__ void repack_w_bf16(const float* __restrict__ w,
                              __hip_bfloat16* __restrict__ wt,
                              int COUT, int CIN, int CINPAD) {
  const int idx = blockIdx.x * 256 + threadIdx.x;
  const int n = 9 * COUT * CINPAD;
  if (idx >= n) return;
  const int t = idx / (COUT * CINPAD);
  const int rem = idx - t * (COUT * CINPAD);
  const int co = rem / CINPAD;
  const int ci = rem - co * CINPAD;
  const float v = (ci < CIN) ? w[(size_t)(co * CIN + ci) * 9 + t] : 0.0f;
  wt[idx] = __float2bfloat16(v);
}

// ---------------------------------------------------------------------------
// conv_mfma: implicit-GEMM 3x3 SAME conv, bf16 NHWC in -> bf16 NHWC out.
// Block: 256 thr = 4 waves; out tile 16x16 px; wave w owns y-rows 4w..4w+3.
// K loop: cin blocks of 32; per cb stage A halo (18x18 px, 32ch) and W chunk
// ([9][COUT][32]) in LDS as SoA 16B chunks (2-way max bank aliasing).
// MFMA 16x16x32 bf16: A[m=px_x][k=cin], B[k][n=cout].
// ---------------------------------------------------------------------------
template <int CINPAD, int COUT, bool LEAKY>
__global__ __launch_bounds__(256, 2) void conv_mfma(
    const uint4* __restrict__ inq,          // bf16 NHWC, CINPAD ch/px
    const __hip_bfloat16* __restrict__ wt,  // [9][COUT][CINPAD]
    const float* __restrict__ bias,
    __hip_bfloat16* __restrict__ out) {     // bf16 NHWC, COUT ch/px
  constexpr int NT = COUT / 16;
  constexpr int NCB = CINPAD / 32;
  constexpr int QSTRIDE_A = 324;          // 18*18 px slots per q-plane
  __shared__ uint4 sA[4 * QSTRIDE_A];     // [q][p]
  __shared__ uint4 sW[4 * 9 * COUT];      // [q][t][co]

  const int tid = threadIdx.x;
  const int lane = tid & 63, w = tid >> 6;
  const int m = lane & 15, q = lane >> 4;
  const int x0 = blockIdx.x * 16, y0 = blockIdx.y * 16, b = blockIdx.z;
  const uint4* wq = (const uint4*)wt;

  float4_t acc[4][NT];
#pragma unroll
  for (int my = 0; my < 4; ++my)
#pragma unroll
    for (int nt = 0; nt < NT; ++nt) acc[my][nt] = (float4_t)0.0f;

  for (int cb = 0; cb < NCB; ++cb) {
    __syncthreads();
    // --- stage A halo tile: 18x18 px, chunks cb*4 .. cb*4+3 ---
    for (int s = tid; s < 324; s += 256) {
      const int pr = s / 18, pc = s - pr * 18;
      const int gy = y0 - 1 + pr, gx = x0 - 1 + pc;
      uint4 c0, c1, c2, c3;
      if (gy >= 0 && gy < HH && gx >= 0 && gx < WW) {
        const size_t base =
            ((size_t)(b * HH + gy) * WW + gx) * (CINPAD / 8) + cb * 4;
        c0 = inq[base + 0]; c1 = inq[base + 1];
        c2 = inq[base + 2]; c3 = inq[base + 3];
      } else {
        c0.x=c0.y=c0.z=c0.w=0u; c1=c0; c2=c0; c3=c0;
      }
      sA[0 * QSTRIDE_A + s] = c0;
      sA[1 * QSTRIDE_A + s] = c1;
      sA[2 * QSTRIDE_A + s] = c2;
      sA[3 * QSTRIDE_A + s] = c3;
    }
    // --- stage W chunk: [9][COUT][32ch] ---
    for (int s = tid; s < 9 * COUT; s += 256) {
      const int t = s / COUT, co = s - t * COUT;
      const size_t base = ((size_t)(t * COUT + co) * CINPAD + cb * 32) / 8;
      const uint4 c0 = wq[base + 0], c1 = wq[base + 1];
      const uint4 c2 = wq[base + 2], c3 = wq[base + 3];
      sW[(0 * 9 + t) * COUT + co] = c0;
      sW[(1 * 9 + t) * COUT + co] = c1;
      sW[(2 * 9 + t) * COUT + co] = c2;
      sW[(3 * 9 + t) * COUT + co] = c3;
    }
    __syncthreads();

#pragma unroll
    for (int t = 0; t < 9; ++t) {
      const int dy = t / 3 - 1, dx = t % 3 - 1;
      short8_t bf[NT];
#pragma unroll
      for (int nt = 0; nt < NT; ++nt) {
        bf[nt] = *(const short8_t*)&sW[(q * 9 + t) * COUT + nt * 16 + m];
      }
#pragma unroll
      for (int my = 0; my < 4; ++my) {
        const int row = 4 * w + my + dy + 1;
        const int col = m + dx + 1;
        const short8_t af =
            *(const short8_t*)&sA[q * QSTRIDE_A + row * 18 + col];
#pragma unroll
        for (int nt = 0; nt < NT; ++nt) {
          acc[my][nt] = __builtin_amdgcn_mfma_f32_16x16x32_bf16(
              af, bf[nt], acc[my][nt], 0, 0, 0);
        }
      }
    }
  }

  // --- epilogue: bias + leaky + bf16 NHWC store ---
  // C/D layout: col(n)=lane&15, row(m)=(lane>>4)*4+r
#pragma unroll
  for (int my = 0; my < 4; ++my) {
    const int y = y0 + 4 * w + my;
#pragma unroll
    for (int nt = 0; nt < NT; ++nt) {
      const int co = nt * 16 + m;
      const float bv = bias[co];
#pragma unroll
      for (int r = 0; r < 4; ++r) {
        const int x = x0 + q * 4 + r;
        float v = acc[my][nt][r] + bv;
        if (LEAKY) v = (v >= 0.0f) ? v : 0.1f * v;
        out[((size_t)(b * HH + y) * WW + x) * COUT + co] = __float2bfloat16(v);
      }
    }
  }
}

// ---------------------------------------------------------------------------
// conv4: 32 -> 2, direct, bf16 NHWC in -> fp32 NCHW out (final flow).
// ---------------------------------------------------------------------------
__global__ __launch_bounds__(256, 2) void conv4_kernel(
    const uint4* __restrict__ inq,          // h3, 32ch/px = 4 uint4
    const __hip_bfloat16* __restrict__ wt,  // [9][2][32]
    const float* __restrict__ bias,
    float* __restrict__ out) {
  __shared__ uint4 sA[4 * 324];
  __shared__ uint4 sW[9 * 2 * 4];  // [t][co][q]
  const int tid = threadIdx.x;
  const int tx = tid & 15, ty = tid >> 4;
  const int x0 = blockIdx.x * 16, y0 = blockIdx.y * 16, b = blockIdx.z;

  for (int s = tid; s < 324; s += 256) {
    const int pr = s / 18, pc = s - pr * 18;
    const int gy = y0 - 1 + pr, gx = x0 - 1 + pc;
    uint4 c0, c1, c2, c3;
    if (gy >= 0 && gy < HH && gx >= 0 && gx < WW) {
      const size_t base = ((size_t)(b * HH + gy) * WW + gx) * 4;
      c0 = inq[base + 0]; c1 = inq[base + 1];
      c2 = inq[base + 2]; c3 = inq[base + 3];
    } else {
      c0.x=c0.y=c0.z=c0.w=0u; c1=c0; c2=c0; c3=c0;
    }
    sA[0 * 324 + s] = c0; sA[1 * 324 + s] = c1;
    sA[2 * 324 + s] = c2; sA[3 * 324 + s] = c3;
  }
  if (tid < 72) sW[tid] = ((const uint4*)wt)[tid];
  __syncthreads();

  float acc0 = bias[0], acc1 = bias[1];
#pragma unroll
  for (int t = 0; t < 9; ++t) {
    const int dy = t / 3 - 1, dx = t % 3 - 1;
    const int row = ty + dy + 1, col = tx + dx + 1;
#pragma unroll
    for (int qi = 0; qi < 4; ++qi) {
      const short8_t a = *(const short8_t*)&sA[qi * 324 + row * 18 + col];
      const short8_t w0 = *(const short8_t*)&sW[(t * 2 + 0) * 4 + qi];
      const short8_t w1 = *(const short8_t*)&sW[(t * 2 + 1) * 4 + qi];
#pragma unroll
      for (int j = 0; j < 8; ++j) {
        const float av = bf2f(a[j]);
        acc0 += av * bf2f(w0[j]);
        acc1 += av * bf2f(w1[j]);
      }
    }
  }
  const int y = y0 + ty, x = x0 + tx;
  out[((size_t)(b * 2 + 0) * HH + y) * WW + x] = acc0;
  out[((size_t)(b * 2 + 1) * HH + y) * WW + x] = acc1;
}

// ---------------------------------------------------------------------------
// Launch
// ---------------------------------------------------------------------------
extern "C" void kernel_launch(void* const* d_in, const int* in_sizes, int n_in,
                              void* d_out, int out_size, void* d_ws,
                              size_t ws_size, hipStream_t stream) {
  const float* x1 = (const float*)d_in[0];
  const float* x2 = (const float*)d_in[1];
  const float* w1 = (const float*)d_in[2];
  const float* b1 = (const float*)d_in[3];
  const float* w2 = (const float*)d_in[4];
  const float* b2 = (const float*)d_in[5];
  const float* w3 = (const float*)d_in[6];
  const float* b3 = (const float*)d_in[7];
  const float* w4 = (const float*)d_in[8];
  const float* b4 = (const float*)d_in[9];
  float* out = (float*)d_out;

  // Workspace (bytes):
  //  A0  [0, 102760448)              bf16 NHWC 224ch concat (x1+corr+pad)
  //  h1  [102760448, 132120576)      bf16 NHWC 64ch
  //  wt1 [132120576, +258048)        bf16 [9][64][224]
  //  wt2 ... [9][64][64], wt3 [9][32][64], wt4 [9][2][32]
  //  h2 reuses A0[0, 29360128)  (A0 dead after conv1)
  //  h3 reuses A0[29360128, 44040192)
  char* ws = (char*)d_ws;
  __hip_bfloat16* A0 = (__hip_bfloat16*)ws;
  const size_t A0_BYTES = (size_t)BN * HH * WW * CINP1 * 2;  // 102,760,448
  __hip_bfloat16* h1 = (__hip_bfloat16*)(ws + A0_BYTES);
  const size_t H1_BYTES = (size_t)BN * HH * WW * 64 * 2;     // 29,360,128
  __hip_bfloat16* wt1 = (__hip_bfloat16*)(ws + A0_BYTES + H1_BYTES);
  __hip_bfloat16* wt2 = wt1 + 9 * 64 * CINP1;
  __hip_bfloat16* wt3 = wt2 + 9 * 64 * 64;
  __hip_bfloat16* wt4 = wt3 + 9 * 32 * 64;
  __hip_bfloat16* h2 = (__hip_bfloat16*)ws;
  __hip_bfloat16* h3 = (__hip_bfloat16*)(ws + H1_BYTES);

  // weight repacks (tiny)
  {
    int n1 = 9 * 64 * CINP1;
    repack_w_bf16<<<(n1 + 255) / 256, 256, 0, stream>>>(w1, wt1, 64, 209, CINP1);
    int n2 = 9 * 64 * 64;
    repack_w_bf16<<<(n2 + 255) / 256, 256, 0, stream>>>(w2, wt2, 64, 64, 64);
    int n3 = 9 * 32 * 64;
    repack_w_bf16<<<(n3 + 255) / 256, 256, 0, stream>>>(w3, wt3, 32, 64, 64);
    int n4 = 9 * 2 * 32;
    repack_w_bf16<<<(n4 + 255) / 256, 256, 0, stream>>>(w4, wt4, 2, 32, 32);
  }

  // x1 -> A0 (bf16 NHWC) + zero pad channels
  convert_x1<<<BN * HH * WW / 256, 256, 0, stream>>>(x1, (uint4*)A0);

  // correlation -> A0 channels 128..208 (single pass, d split over 3 waves)
  corr_v3<<<dim3(WW / 16, HH / 16, BN), dim3(192), 0, stream>>>(x1, x2, A0);

  const dim3 grid(WW / 16, HH / 16, BN);  // 14 x 8 x 8 = 896 blocks
  conv_mfma<CINP1, 64, true>
      <<<grid, 256, 0, stream>>>((const uint4*)A0, wt1, b1, h1);
  conv_mfma<64, 64, true>
      <<<grid, 256, 0, stream>>>((const uint4*)h1, wt2, b2, h2);
  conv_mfma<64, 32, true>
      <<<grid, 256, 0, stream>>>((const uint4*)h2, wt3, b3, h3);
  conv4_kernel<<<grid, 256, 0, stream>>>((const uint4*)h3, wt4, b4, out);
}